// Round 3
// baseline (545.857 us; speedup 1.0000x reference)
//
#include <hip/hip_runtime.h>
#include <hip/hip_bf16.h>
#include <stdint.h>

#define LL 2048
#define SS 2048
#define HH 8
#define EE 64
#define RSG 512   // global row stride in elements (H*E)

typedef float v4f  __attribute__((ext_vector_type(4)));
typedef float v16f __attribute__((ext_vector_type(16)));
typedef short s4v  __attribute__((ext_vector_type(4)));
typedef short s8v  __attribute__((ext_vector_type(8)));

// fp32 -> bf16 bits, round-to-nearest-even
__device__ __forceinline__ short f2bf(float f) {
    unsigned u = __float_as_uint(f);
    u = (u + 0x7fffu + ((u >> 16) & 1u)) >> 16;
    return (short)u;
}

__device__ __forceinline__ s4v pack4bf(float a, float b, float c, float d) {
    float2 ab = make_float2(a, b), cd = make_float2(c, d);
    __hip_bfloat162 r0 = __float22bfloat162_rn(ab);
    __hip_bfloat162 r1 = __float22bfloat162_rn(cd);
    s4v r;
    __builtin_memcpy(&r, &r0, 4);
    __builtin_memcpy(((char*)&r) + 4, &r1, 4);
    return r;
}

// ---------------- prepass ----------------
// K: fp32 -> bf16, natural layout.
// Vimg per (b,h,64-row tile): rows e=0..63, each row 8 chunks of 16B.
// Chunk at position pos holds logical chunk c = pos ^ (e&7).
// Logical slot u = 8c + j holds V[s][e] with
//   s = 16*(c>>1) + 4*(c&1) + 8*(j>>2) + (j&3)          (the PV k-permutation)
__global__ __launch_bounds__(256)
void dsattn_prep(const float* __restrict__ kk, const float* __restrict__ vv,
                 short* __restrict__ kbf, short* __restrict__ vimg)
{
    __shared__ float T[64][68];
    const int t = threadIdx.x;
    const int blk = blockIdx.x;
    if (blk < 1024) {
        const float* src = kk + (size_t)blk * 4096;
        short* dst = kbf + (size_t)blk * 4096;
        #pragma unroll
        for (int c = 0; c < 4; ++c) {
            v4f d = *(const v4f*)(src + (c * 256 + t) * 4);
            *(s4v*)(dst + (c * 256 + t) * 4) = pack4bf(d[0], d[1], d[2], d[3]);
        }
    } else {
        const int vb = blk - 1024;           // (b*8 + h)*32 + ts
        const int b = vb >> 8, h = (vb >> 5) & 7, ts = vb & 31;
        const float* vp = vv + ((size_t)b * SS + ts * 64) * RSG + h * EE;
        #pragma unroll
        for (int c = 0; c < 4; ++c) {
            int idx = c * 256 + t, s = idx >> 4, e0 = (idx & 15) << 2;
            *(v4f*)&T[s][e0] = *(const v4f*)(vp + (size_t)s * RSG + e0);
        }
        __syncthreads();
        short* dst = vimg + (size_t)vb * 4096;
        #pragma unroll
        for (int half = 0; half < 2; ++half) {
            int ci = half * 256 + t;         // 16B chunk index 0..511
            int e = ci >> 3, pos = ci & 7;
            int c = pos ^ (e & 7);
            int sbase = 16 * (c >> 1) + 4 * (c & 1);
            s8v ov;
            #pragma unroll
            for (int j = 0; j < 8; ++j) {
                int s = sbase + 8 * (j >> 2) + (j & 3);
                ov[j] = f2bf(T[s][e]);
            }
            *(s8v*)(dst + ci * 8) = ov;
        }
    }
}

// ---------------- main: 128 Q rows/block, 4 waves x 32 rows, all-32x32x16 MFMA
// Cross-tile software pipeline: iteration it computes QK^T/exp2/pack of tile it
// AND PV of tile it-1 (independent register stream -> fills the serial-chain
// stalls).  4-slot LDS ring, STAGE after the barrier, counted vmcnt(4):
// guarantees tile it landed while tile it+2's 4 loads stay in flight.
// XCD-bijective 1-D grid: each XCD owns 4 contiguous (b,h) panels.
__global__ __launch_bounds__(256, 2)
void dsattn_main(const float* __restrict__ q, const short* __restrict__ kbf,
                 const short* __restrict__ vimg, const float* __restrict__ tau,
                 float* __restrict__ out)
{
    __shared__ short KV[4][8192];   // per slot: [0..4095] K tile, [4096..8191] V image

    const int t    = threadIdx.x;
    const int lane = t & 63;
    const int w    = t >> 6;
    const int l31  = lane & 31;
    const int hi   = lane >> 5;

    // XCD-aware decode: 512 blocks, 8 XCDs, 64 consecutive work-units per XCD.
    const int hw = blockIdx.x;
    const int wu = (hw & 7) * 64 + (hw >> 3);
    const int mt = wu & 15;
    const int h  = (wu >> 4) & 7;
    const int b  = wu >> 7;

    const float scf = 0.125f * 1.44269504088896f * tau[b];  // tau*scale*log2e folded into Q

    // ---- Q B-frags: lane holds Q[w*32+l31][e = 16ks + 8hi + j], pre-scaled ----
    s8v qf[4];
    {
        const float* qb = q + ((size_t)b * LL + (size_t)mt * 128 + w * 32 + l31) * RSG
                            + h * EE + 8 * hi;
        #pragma unroll
        for (int ks = 0; ks < 4; ++ks) {
            v4f a0 = *(const v4f*)(qb + 16 * ks);
            v4f a1 = *(const v4f*)(qb + 16 * ks + 4);
            s4v p0 = pack4bf(a0[0] * scf, a0[1] * scf, a0[2] * scf, a0[3] * scf);
            s4v p1 = pack4bf(a1[0] * scf, a1[1] * scf, a1[2] * scf, a1[3] * scf);
            s8v f;
            #pragma unroll
            for (int j = 0; j < 4; ++j) { f[j] = p0[j]; f[4 + j] = p1[j]; }
            qf[ks] = f;
        }
    }

    // ---- staging source pointers (waves 0,1: K with src-side swizzle; 2,3: V linear) ----
    const char* gsrc;
    int jstr, tstr;
    if (w < 2) {
        int i = w * 256 + lane;
        int row = i >> 3;
        int c = (i & 7) ^ (row & 7);
        gsrc = (const char*)(kbf + (size_t)b * (SS * RSG) + h * EE) + row * (RSG * 2) + c * 16;
        jstr = 8 * RSG * 2;
        tstr = 64 * RSG * 2;
    } else {
        int i2 = (w - 2) * 256 + lane;
        gsrc = (const char*)(vimg + (((size_t)b * HH + h) * 32) * 4096) + i2 * 16;
        jstr = 1024; tstr = 8192;
    }

    #define STAGE(slot)                                                                   \
        {                                                                                 \
            _Pragma("unroll")                                                             \
            for (int j = 0; j < 4; ++j) {                                                 \
                __builtin_amdgcn_global_load_lds(                                         \
                    (const __attribute__((address_space(1))) unsigned*)(gsrc + j * jstr), \
                    (__attribute__((address_space(3))) unsigned*)&KV[slot][w * 2048 + j * 512], \
                    16, 0, 0);                                                            \
            }                                                                             \
            gsrc += tstr;                                                                 \
        }

    v16f oacc[2];
    #pragma unroll
    for (int mb = 0; mb < 2; ++mb)
        #pragma unroll
        for (int r = 0; r < 16; ++r) oacc[mb][r] = 0.0f;
    float rsum = 0.0f;

    // per-lane LDS read offsets (shorts): row l31 (+32 per Mblk), chunk pos swizzled
    const int xo = l31 & 7;
    const int rbase = l31 * 64;
    int kpos[4];
    #pragma unroll
    for (int ks = 0; ks < 4; ++ks) kpos[ks] = (((hi + 2 * ks) & 7) ^ xo) * 8;

    // Drain Q loads so loop vmcnt counts see ONLY staging loads, then fill pipe 2 deep.
    asm volatile("s_waitcnt vmcnt(0)" ::: "memory");
    __builtin_amdgcn_sched_barrier(0);
    STAGE(0);
    STAGE(1);

    // QK^T -> st for tile in slot P_; then exp2/rowsum/pack into pfp
    #define QK_TILE(P_)                                                                   \
        {                                                                                 \
            const short* Kp = &KV[P_][0];                                                 \
            _Pragma("unroll")                                                             \
            for (int mb = 0; mb < 2; ++mb) {                                              \
                v16f z;                                                                   \
                _Pragma("unroll")                                                         \
                for (int r = 0; r < 16; ++r) z[r] = 0.0f;                                 \
                _Pragma("unroll")                                                         \
                for (int ks = 0; ks < 4; ++ks) {                                          \
                    s8v kf = *(const s8v*)&Kp[mb * 2048 + rbase + kpos[ks]];              \
                    z = __builtin_amdgcn_mfma_f32_32x32x16_bf16(kf, qf[ks], z, 0, 0, 0);  \
                }                                                                         \
                st[mb] = z;                                                               \
            }                                                                             \
        }

    #define EXP_PACK()                                                                    \
        {                                                                                 \
            _Pragma("unroll")                                                             \
            for (int mb = 0; mb < 2; ++mb)                                                \
                _Pragma("unroll")                                                         \
                for (int r = 0; r < 16; ++r)                                              \
                    st[mb][r] = __builtin_amdgcn_exp2f(st[mb][r]);                        \
            float s0 = 0.f, s1 = 0.f;                                                     \
            _Pragma("unroll")                                                             \
            for (int r = 0; r < 16; ++r) { s0 += st[0][r]; s1 += st[1][r]; }              \
            rsum += s0 + s1;                                                              \
            _Pragma("unroll")                                                             \
            for (int tt = 0; tt < 4; ++tt) {                                              \
                int o = 8 * (tt & 1);                                                     \
                const v16f& sv = st[tt >> 1];                                             \
                s4v lo = pack4bf(sv[o + 0], sv[o + 1], sv[o + 2], sv[o + 3]);             \
                s4v hs = pack4bf(sv[o + 4], sv[o + 5], sv[o + 6], sv[o + 7]);             \
                s8v f;                                                                    \
                _Pragma("unroll")                                                         \
                for (int j = 0; j < 4; ++j) { f[j] = lo[j]; f[4 + j] = hs[j]; }           \
                pfp[tt] = f;                                                              \
            }                                                                             \
        }

    #define PV_TILE(P_)                                                                   \
        {                                                                                 \
            const short* Vp = &KV[P_][4096];                                              \
            _Pragma("unroll")                                                             \
            for (int mb = 0; mb < 2; ++mb) {                                              \
                v16f acc = oacc[mb];                                                      \
                _Pragma("unroll")                                                         \
                for (int ks = 0; ks < 4; ++ks) {                                          \
                    s8v vf = *(const s8v*)&Vp[mb * 2048 + rbase + kpos[ks]];              \
                    acc = __builtin_amdgcn_mfma_f32_32x32x16_bf16(vf, pfp[ks], acc, 0, 0, 0); \
                }                                                                         \
                oacc[mb] = acc;                                                           \
            }                                                                             \
        }

    s8v pfp[4];   // P frags of the PREVIOUS tile (PV consumes, EXP_PACK produces)

    // ---- peeled tile 0: QK + exp/pack only (no PV yet) ----
    {
        __builtin_amdgcn_sched_barrier(0);
        // outstanding = 8 (tiles 0,1); vmcnt(4) -> tile 0 landed, tile 1 flying
        asm volatile("s_waitcnt vmcnt(4)" ::: "memory");
        __builtin_amdgcn_s_barrier();
        __builtin_amdgcn_sched_barrier(0);
        STAGE(2);                                          // tile 2 -> slot 2
        v16f st[2];
        QK_TILE(0);
        EXP_PACK();
    }

    // ---- steady state: QK/exp/pack tile it  ||  PV tile it-1 ----
    #pragma unroll 4
    for (int it = 1; it < 32; ++it) {
        const int p   = it & 3;
        const int pm1 = (it - 1) & 3;

        __builtin_amdgcn_sched_barrier(0);
        // outstanding <= 8 (tiles it, it+1); vmcnt(4) -> tile it landed, it+1 flying.
        if (it <= 30) asm volatile("s_waitcnt vmcnt(4)" ::: "memory");
        else          asm volatile("s_waitcnt vmcnt(0)" ::: "memory");  // it=31: last tile
        __builtin_amdgcn_s_barrier();
        __builtin_amdgcn_sched_barrier(0);

        // stage tile it+2 into slot (it+2)&3 = (it-2)&3: its last reader PV(it-2)
        // finished during iter it-1, published by the barrier above.
        if (it <= 29) STAGE((it + 2) & 3);

        v16f st[2];
        QK_TILE(p);        // fresh ds_reads + 2x4 MFMA chain (tile it)
        PV_TILE(pm1);      // independent: pfp regs + long-resident V (tile it-1)
        EXP_PACK();        // trans+VALU for tile it -> new pfp (after PV consumed old)
    }

    // ---- epilogue: PV of tile 31 (slot 3) ----
    PV_TILE(3);

    // ---- denominator (single cross-half reduce) and store O^T -> O ----
    rsum += __shfl_xor(rsum, 32);
    const float inv = 1.0f / rsum;
    float* ob = out + ((size_t)b * LL + (size_t)mt * 128 + w * 32 + l31) * RSG + h * EE;
    #pragma unroll
    for (int mb = 0; mb < 2; ++mb)
        #pragma unroll
        for (int rq = 0; rq < 4; ++rq) {
            int e0 = 32 * mb + 8 * rq + 4 * hi;     // C-layout row = (reg&3)+8*(reg>>2)+4*hi
            v4f o4 = { oacc[mb][4 * rq + 0] * inv, oacc[mb][4 * rq + 1] * inv,
                       oacc[mb][4 * rq + 2] * inv, oacc[mb][4 * rq + 3] * inv };
            *(v4f*)(ob + e0) = o4;
        }
}

extern "C" void kernel_launch(void* const* d_in, const int* in_sizes, int n_in,
                              void* d_out, int out_size, void* d_ws, size_t ws_size,
                              hipStream_t stream) {
    const float* q     = (const float*)d_in[0];
    const float* k     = (const float*)d_in[1];
    const float* v     = (const float*)d_in[2];
    // d_in[3] = attn_mask (unused); d_in[5] = delta (drops out of softmax exactly)
    const float* tau   = (const float*)d_in[4];
    float* out = (float*)d_out;

    short* kbf  = (short*)d_ws;                   // 4*2048*512 bf16 = 8.39 MB
    short* vimg = kbf + (size_t)4 * SS * RSG;     // 8.39 MB

    dsattn_prep<<<dim3(2048), dim3(256), 0, stream>>>(k, v, kbf, vimg);
    dsattn_main<<<dim3(512), dim3(256), 0, stream>>>(q, kbf, vimg, tau, out);
}

// Round 4
// 137.619 us; speedup vs baseline: 3.9664x; 3.9664x over previous
//
#include <hip/hip_runtime.h>
#include <hip/hip_bf16.h>
#include <stdint.h>

#define LL 2048
#define SS 2048
#define HH 8
#define EE 64
#define RSG 512   // global row stride in elements (H*E)

typedef float v4f  __attribute__((ext_vector_type(4)));
typedef float v16f __attribute__((ext_vector_type(16)));
typedef short s4v  __attribute__((ext_vector_type(4)));
typedef short s8v  __attribute__((ext_vector_type(8)));

// fp32 -> bf16 bits, round-to-nearest-even
__device__ __forceinline__ short f2bf(float f) {
    unsigned u = __float_as_uint(f);
    u = (u + 0x7fffu + ((u >> 16) & 1u)) >> 16;
    return (short)u;
}

__device__ __forceinline__ s4v pack4bf(float a, float b, float c, float d) {
    float2 ab = make_float2(a, b), cd = make_float2(c, d);
    __hip_bfloat162 r0 = __float22bfloat162_rn(ab);
    __hip_bfloat162 r1 = __float22bfloat162_rn(cd);
    s4v r;
    __builtin_memcpy(&r, &r0, 4);
    __builtin_memcpy(((char*)&r) + 4, &r1, 4);
    return r;
}

// ---------------- prepass ----------------
// K: fp32 -> bf16, natural layout.
// Vimg per (b,h,64-row tile): rows e=0..63, each row 8 chunks of 16B.
// Chunk at position pos holds logical chunk c = pos ^ (e&7).
// Logical slot u = 8c + j holds V[s][e] with
//   s = 16*(c>>1) + 4*(c&1) + 8*(j>>2) + (j&3)          (the PV k-permutation)
__global__ __launch_bounds__(256)
void dsattn_prep(const float* __restrict__ kk, const float* __restrict__ vv,
                 short* __restrict__ kbf, short* __restrict__ vimg)
{
    __shared__ float T[64][68];
    const int t = threadIdx.x;
    const int blk = blockIdx.x;
    if (blk < 1024) {
        const float* src = kk + (size_t)blk * 4096;
        short* dst = kbf + (size_t)blk * 4096;
        #pragma unroll
        for (int c = 0; c < 4; ++c) {
            v4f d = *(const v4f*)(src + (c * 256 + t) * 4);
            *(s4v*)(dst + (c * 256 + t) * 4) = pack4bf(d[0], d[1], d[2], d[3]);
        }
    } else {
        const int vb = blk - 1024;           // (b*8 + h)*32 + ts
        const int b = vb >> 8, h = (vb >> 5) & 7, ts = vb & 31;
        const float* vp = vv + ((size_t)b * SS + ts * 64) * RSG + h * EE;
        #pragma unroll
        for (int c = 0; c < 4; ++c) {
            int idx = c * 256 + t, s = idx >> 4, e0 = (idx & 15) << 2;
            *(v4f*)&T[s][e0] = *(const v4f*)(vp + (size_t)s * RSG + e0);
        }
        __syncthreads();
        short* dst = vimg + (size_t)vb * 4096;
        #pragma unroll
        for (int half = 0; half < 2; ++half) {
            int ci = half * 256 + t;         // 16B chunk index 0..511
            int e = ci >> 3, pos = ci & 7;
            int c = pos ^ (e & 7);
            int sbase = 16 * (c >> 1) + 4 * (c & 1);
            s8v ov;
            #pragma unroll
            for (int j = 0; j < 8; ++j) {
                int s = sbase + 8 * (j >> 2) + (j & 3);
                ov[j] = f2bf(T[s][e]);
            }
            *(s8v*)(dst + ci * 8) = ov;
        }
    }
}

// ---------------- main: 128 Q rows/block, 4 waves x 32 rows, all-32x32x16 MFMA
// Cross-tile software pipeline (ROLLED loop — unroll 4 caused 4x overlapping
// st[] live ranges -> 433 MB scratch spill in the previous round):
// iteration it runs PV of tile it-1, then QK^T of tile it, then exp2/pack.
// PV-first ends pfp's live range before st's begins (min register pressure);
// the scheduler still interleaves PV's independent MFMAs into QK's stalls.
// 4-slot LDS ring, STAGE after the barrier, counted vmcnt(4).
// XCD-bijective 1-D grid: each XCD owns 4 contiguous (b,h) panels.
__global__ __launch_bounds__(256, 2)
void dsattn_main(const float* __restrict__ q, const short* __restrict__ kbf,
                 const short* __restrict__ vimg, const float* __restrict__ tau,
                 float* __restrict__ out)
{
    __shared__ short KV[4][8192];   // per slot: [0..4095] K tile, [4096..8191] V image

    const int t    = threadIdx.x;
    const int lane = t & 63;
    const int w    = t >> 6;
    const int l31  = lane & 31;
    const int hi   = lane >> 5;

    // XCD-aware decode: 512 blocks, 8 XCDs, 64 consecutive work-units per XCD.
    const int hw = blockIdx.x;
    const int wu = (hw & 7) * 64 + (hw >> 3);
    const int mt = wu & 15;
    const int h  = (wu >> 4) & 7;
    const int b  = wu >> 7;

    const float scf = 0.125f * 1.44269504088896f * tau[b];  // tau*scale*log2e folded into Q

    // ---- Q B-frags: lane holds Q[w*32+l31][e = 16ks + 8hi + j], pre-scaled ----
    s8v qf[4];
    {
        const float* qb = q + ((size_t)b * LL + (size_t)mt * 128 + w * 32 + l31) * RSG
                            + h * EE + 8 * hi;
        #pragma unroll
        for (int ks = 0; ks < 4; ++ks) {
            v4f a0 = *(const v4f*)(qb + 16 * ks);
            v4f a1 = *(const v4f*)(qb + 16 * ks + 4);
            s4v p0 = pack4bf(a0[0] * scf, a0[1] * scf, a0[2] * scf, a0[3] * scf);
            s4v p1 = pack4bf(a1[0] * scf, a1[1] * scf, a1[2] * scf, a1[3] * scf);
            s8v f;
            #pragma unroll
            for (int j = 0; j < 4; ++j) { f[j] = p0[j]; f[4 + j] = p1[j]; }
            qf[ks] = f;
        }
    }

    // ---- staging source pointers (waves 0,1: K with src-side swizzle; 2,3: V linear) ----
    const char* gsrc;
    int jstr, tstr;
    if (w < 2) {
        int i = w * 256 + lane;
        int row = i >> 3;
        int c = (i & 7) ^ (row & 7);
        gsrc = (const char*)(kbf + (size_t)b * (SS * RSG) + h * EE) + row * (RSG * 2) + c * 16;
        jstr = 8 * RSG * 2;
        tstr = 64 * RSG * 2;
    } else {
        int i2 = (w - 2) * 256 + lane;
        gsrc = (const char*)(vimg + (((size_t)b * HH + h) * 32) * 4096) + i2 * 16;
        jstr = 1024; tstr = 8192;
    }

    #define STAGE(slot)                                                                   \
        {                                                                                 \
            _Pragma("unroll")                                                             \
            for (int j = 0; j < 4; ++j) {                                                 \
                __builtin_amdgcn_global_load_lds(                                         \
                    (const __attribute__((address_space(1))) unsigned*)(gsrc + j * jstr), \
                    (__attribute__((address_space(3))) unsigned*)&KV[slot][w * 2048 + j * 512], \
                    16, 0, 0);                                                            \
            }                                                                             \
            gsrc += tstr;                                                                 \
        }

    v16f oacc[2];
    #pragma unroll
    for (int mb = 0; mb < 2; ++mb)
        #pragma unroll
        for (int r = 0; r < 16; ++r) oacc[mb][r] = 0.0f;
    float rsum = 0.0f;

    // per-lane LDS read offsets (shorts): row l31 (+32 per Mblk), chunk pos swizzled
    const int xo = l31 & 7;
    const int rbase = l31 * 64;
    int kpos[4];
    #pragma unroll
    for (int ks = 0; ks < 4; ++ks) kpos[ks] = (((hi + 2 * ks) & 7) ^ xo) * 8;

    // Drain Q loads so loop vmcnt counts see ONLY staging loads, then fill pipe 2 deep.
    asm volatile("s_waitcnt vmcnt(0)" ::: "memory");
    __builtin_amdgcn_sched_barrier(0);
    STAGE(0);
    STAGE(1);

    // QK^T -> st for tile in slot P_; then exp2/rowsum/pack into pfp
    #define QK_TILE(P_)                                                                   \
        {                                                                                 \
            const short* Kp = &KV[P_][0];                                                 \
            _Pragma("unroll")                                                             \
            for (int mb = 0; mb < 2; ++mb) {                                              \
                v16f z;                                                                   \
                _Pragma("unroll")                                                         \
                for (int r = 0; r < 16; ++r) z[r] = 0.0f;                                 \
                _Pragma("unroll")                                                         \
                for (int ks = 0; ks < 4; ++ks) {                                          \
                    s8v kf = *(const s8v*)&Kp[mb * 2048 + rbase + kpos[ks]];              \
                    z = __builtin_amdgcn_mfma_f32_32x32x16_bf16(kf, qf[ks], z, 0, 0, 0);  \
                }                                                                         \
                st[mb] = z;                                                               \
            }                                                                             \
        }

    #define EXP_PACK()                                                                    \
        {                                                                                 \
            _Pragma("unroll")                                                             \
            for (int mb = 0; mb < 2; ++mb)                                                \
                _Pragma("unroll")                                                         \
                for (int r = 0; r < 16; ++r)                                              \
                    st[mb][r] = __builtin_amdgcn_exp2f(st[mb][r]);                        \
            float s0 = 0.f, s1 = 0.f;                                                     \
            _Pragma("unroll")                                                             \
            for (int r = 0; r < 16; ++r) { s0 += st[0][r]; s1 += st[1][r]; }              \
            rsum += s0 + s1;                                                              \
            _Pragma("unroll")                                                             \
            for (int tt = 0; tt < 4; ++tt) {                                              \
                int o = 8 * (tt & 1);                                                     \
                const v16f& sv = st[tt >> 1];                                             \
                s4v lo = pack4bf(sv[o + 0], sv[o + 1], sv[o + 2], sv[o + 3]);             \
                s4v hs = pack4bf(sv[o + 4], sv[o + 5], sv[o + 6], sv[o + 7]);             \
                s8v f;                                                                    \
                _Pragma("unroll")                                                         \
                for (int j = 0; j < 4; ++j) { f[j] = lo[j]; f[4 + j] = hs[j]; }           \
                pfp[tt] = f;                                                              \
            }                                                                             \
        }

    #define PV_TILE(P_)                                                                   \
        {                                                                                 \
            const short* Vp = &KV[P_][4096];                                              \
            _Pragma("unroll")                                                             \
            for (int mb = 0; mb < 2; ++mb) {                                              \
                v16f acc = oacc[mb];                                                      \
                _Pragma("unroll")                                                         \
                for (int ks = 0; ks < 4; ++ks) {                                          \
                    s8v vf = *(const s8v*)&Vp[mb * 2048 + rbase + kpos[ks]];              \
                    acc = __builtin_amdgcn_mfma_f32_32x32x16_bf16(vf, pfp[ks], acc, 0, 0, 0); \
                }                                                                         \
                oacc[mb] = acc;                                                           \
            }                                                                             \
        }

    s8v pfp[4];   // P frags of the PREVIOUS tile (PV consumes, EXP_PACK produces)

    // ---- peeled tile 0: QK + exp/pack only (no PV yet) ----
    {
        __builtin_amdgcn_sched_barrier(0);
        // outstanding = 8 (tiles 0,1); vmcnt(4) -> tile 0 landed, tile 1 flying
        asm volatile("s_waitcnt vmcnt(4)" ::: "memory");
        __builtin_amdgcn_s_barrier();
        __builtin_amdgcn_sched_barrier(0);
        STAGE(2);                                          // tile 2 -> slot 2
        v16f st[2];
        QK_TILE(0);
        EXP_PACK();
    }

    // ---- steady state (ROLLED): PV tile it-1  ||  QK/exp/pack tile it ----
    #pragma unroll 1
    for (int it = 1; it < 32; ++it) {
        const int p   = it & 3;
        const int pm1 = (it - 1) & 3;

        __builtin_amdgcn_sched_barrier(0);
        // outstanding <= 8 (tiles it, it+1); vmcnt(4) -> tile it landed, it+1 flying.
        if (it <= 30) asm volatile("s_waitcnt vmcnt(4)" ::: "memory");
        else          asm volatile("s_waitcnt vmcnt(0)" ::: "memory");  // it=31: last tile
        __builtin_amdgcn_s_barrier();
        __builtin_amdgcn_sched_barrier(0);

        // stage tile it+2 into slot (it+2)&3 = (it-2)&3: its last reader PV(it-2)
        // ran during iter it-1; all waves passed the barrier above since.
        if (it <= 29) STAGE((it + 2) & 3);

        v16f st[2];
        PV_TILE(pm1);      // consumes pfp + long-resident V (independent MFMA stream)
        QK_TILE(p);        // fresh ds_reads + 2x4 MFMA chain (tile it)
        EXP_PACK();        // trans+VALU for tile it -> new pfp
    }

    // ---- epilogue: PV of tile 31 (slot 3) ----
    PV_TILE(3);

    // ---- denominator (single cross-half reduce) and store O^T -> O ----
    rsum += __shfl_xor(rsum, 32);
    const float inv = 1.0f / rsum;
    float* ob = out + ((size_t)b * LL + (size_t)mt * 128 + w * 32 + l31) * RSG + h * EE;
    #pragma unroll
    for (int mb = 0; mb < 2; ++mb)
        #pragma unroll
        for (int rq = 0; rq < 4; ++rq) {
            int e0 = 32 * mb + 8 * rq + 4 * hi;     // C-layout row = (reg&3)+8*(reg>>2)+4*hi
            v4f o4 = { oacc[mb][4 * rq + 0] * inv, oacc[mb][4 * rq + 1] * inv,
                       oacc[mb][4 * rq + 2] * inv, oacc[mb][4 * rq + 3] * inv };
            *(v4f*)(ob + e0) = o4;
        }
}

extern "C" void kernel_launch(void* const* d_in, const int* in_sizes, int n_in,
                              void* d_out, int out_size, void* d_ws, size_t ws_size,
                              hipStream_t stream) {
    const float* q     = (const float*)d_in[0];
    const float* k     = (const float*)d_in[1];
    const float* v     = (const float*)d_in[2];
    // d_in[3] = attn_mask (unused); d_in[5] = delta (drops out of softmax exactly)
    const float* tau   = (const float*)d_in[4];
    float* out = (float*)d_out;

    short* kbf  = (short*)d_ws;                   // 4*2048*512 bf16 = 8.39 MB
    short* vimg = kbf + (size_t)4 * SS * RSG;     // 8.39 MB

    dsattn_prep<<<dim3(2048), dim3(256), 0, stream>>>(k, v, kbf, vimg);
    dsattn_main<<<dim3(512), dim3(256), 0, stream>>>(q, kbf, vimg, tau, out);
}

// Round 5
// 136.205 us; speedup vs baseline: 4.0076x; 1.0104x over previous
//
#include <hip/hip_runtime.h>
#include <hip/hip_bf16.h>
#include <stdint.h>

#define LL 2048
#define SS 2048
#define HH 8
#define EE 64
#define RSG 512   // global row stride in elements (H*E)

typedef float v4f  __attribute__((ext_vector_type(4)));
typedef float v16f __attribute__((ext_vector_type(16)));
typedef short s4v  __attribute__((ext_vector_type(4)));
typedef short s8v  __attribute__((ext_vector_type(8)));

// fp32 -> bf16 bits, round-to-nearest-even
__device__ __forceinline__ short f2bf(float f) {
    unsigned u = __float_as_uint(f);
    u = (u + 0x7fffu + ((u >> 16) & 1u)) >> 16;
    return (short)u;
}

__device__ __forceinline__ s4v pack4bf(float a, float b, float c, float d) {
    float2 ab = make_float2(a, b), cd = make_float2(c, d);
    __hip_bfloat162 r0 = __float22bfloat162_rn(ab);
    __hip_bfloat162 r1 = __float22bfloat162_rn(cd);
    s4v r;
    __builtin_memcpy(&r, &r0, 4);
    __builtin_memcpy(((char*)&r) + 4, &r1, 4);
    return r;
}

// ---------------- prepass ----------------
// Both K and V become per-(b,h,64-row-tile) IMAGES in k-chunk-major order so
// that every main-loop ds_read_b128 and every global_load_lds is fully linear
// (zero bank conflicts, zero XOR address math).
//
// K image: chunk u = echunk*64 + srow  holds K[srow][8*echunk .. +8) as bf16.
// V image: chunk u = c*64 + e          holds V[perm(c,j)][e], j=0..7, with
//   perm(c,j) = 16*(c>>1) + 4*(c&1) + 8*(j>>2) + (j&3)   (the PV k-permutation)
__global__ __launch_bounds__(256)
void dsattn_prep(const float* __restrict__ kk, const float* __restrict__ vv,
                 short* __restrict__ kimg, short* __restrict__ vimg)
{
    __shared__ float T[64][68];
    const int t = threadIdx.x;
    const int blk = blockIdx.x;
    if (blk < 1024) {
        const int vb = blk;                  // (b*8 + h)*32 + ts
        const int b = vb >> 8, h = (vb >> 5) & 7, ts = vb & 31;
        const float* kp = kk + ((size_t)b * SS + ts * 64) * RSG + h * EE;
        #pragma unroll
        for (int c = 0; c < 4; ++c) {
            int idx = c * 256 + t, s = idx >> 4, e0 = (idx & 15) << 2;
            *(v4f*)&T[s][e0] = *(const v4f*)(kp + (size_t)s * RSG + e0);
        }
        __syncthreads();
        short* dst = kimg + (size_t)vb * 4096;
        #pragma unroll
        for (int half = 0; half < 2; ++half) {
            int ci = half * 256 + t;         // chunk u = echunk*64 + srow
            int echunk = ci >> 6, srow = ci & 63;
            s8v ov;
            #pragma unroll
            for (int j = 0; j < 8; ++j) ov[j] = f2bf(T[srow][echunk * 8 + j]);
            *(s8v*)(dst + ci * 8) = ov;
        }
    } else {
        const int vb = blk - 1024;           // (b*8 + h)*32 + ts
        const int b = vb >> 8, h = (vb >> 5) & 7, ts = vb & 31;
        const float* vp = vv + ((size_t)b * SS + ts * 64) * RSG + h * EE;
        #pragma unroll
        for (int c = 0; c < 4; ++c) {
            int idx = c * 256 + t, s = idx >> 4, e0 = (idx & 15) << 2;
            *(v4f*)&T[s][e0] = *(const v4f*)(vp + (size_t)s * RSG + e0);
        }
        __syncthreads();
        short* dst = vimg + (size_t)vb * 4096;
        #pragma unroll
        for (int half = 0; half < 2; ++half) {
            int ci = half * 256 + t;         // chunk u = c*64 + e
            int c = ci >> 6, e = ci & 63;
            int sbase = 16 * (c >> 1) + 4 * (c & 1);
            s8v ov;
            #pragma unroll
            for (int j = 0; j < 8; ++j) {
                int s = sbase + 8 * (j >> 2) + (j & 3);
                ov[j] = f2bf(T[s][e]);
            }
            *(s8v*)(dst + ci * 8) = ov;
        }
    }
}

// ---------------- main: 128 Q rows/block, 4 waves x 32 rows, all-32x32x16 MFMA
// Round-1 schedule (best verified): 4-slot LDS ring, depth-3 prefetch,
// counted vmcnt(8) (never 0 in steady state), same-tile QK->exp->PV.
// NEW: k-chunk-major K/V images -> every ds_read_b128 is two contiguous 512B
// runs (zero bank conflicts) and every global_load_lds source is linear.
// XCD-bijective 1-D grid: each XCD owns 4 contiguous (b,h) panels.
__global__ __launch_bounds__(256, 2)
void dsattn_main(const float* __restrict__ q, const short* __restrict__ kimg,
                 const short* __restrict__ vimg, const float* __restrict__ tau,
                 float* __restrict__ out)
{
    __shared__ short KV[4][8192];   // per slot: [0..4095] K image, [4096..8191] V image

    const int t    = threadIdx.x;
    const int lane = t & 63;
    const int w    = t >> 6;
    const int l31  = lane & 31;
    const int hi   = lane >> 5;

    // XCD-aware decode: 512 blocks, 8 XCDs, 64 consecutive work-units per XCD.
    const int hw = blockIdx.x;
    const int wu = (hw & 7) * 64 + (hw >> 3);
    const int mt = wu & 15;
    const int h  = (wu >> 4) & 7;
    const int b  = wu >> 7;

    const float scf = 0.125f * 1.44269504088896f * tau[b];  // tau*scale*log2e folded into Q

    // ---- Q B-frags: lane holds Q[w*32+l31][e = 16ks + 8hi + j], pre-scaled ----
    s8v qf[4];
    {
        const float* qb = q + ((size_t)b * LL + (size_t)mt * 128 + w * 32 + l31) * RSG
                            + h * EE + 8 * hi;
        #pragma unroll
        for (int ks = 0; ks < 4; ++ks) {
            v4f a0 = *(const v4f*)(qb + 16 * ks);
            v4f a1 = *(const v4f*)(qb + 16 * ks + 4);
            s4v p0 = pack4bf(a0[0] * scf, a0[1] * scf, a0[2] * scf, a0[3] * scf);
            s4v p1 = pack4bf(a1[0] * scf, a1[1] * scf, a1[2] * scf, a1[3] * scf);
            s8v f;
            #pragma unroll
            for (int j = 0; j < 4; ++j) { f[j] = p0[j]; f[4 + j] = p1[j]; }
            qf[ks] = f;
        }
    }

    // ---- staging source: fully linear for all waves (K image: w 0,1; V image: w 2,3) ----
    const char* gsrc;
    {
        const size_t pan = (size_t)((b * 8 + h) * 32) * 8192;   // 32 tiles x 8KB
        if (w < 2) gsrc = (const char*)kimg + pan + w * 4096 + lane * 16;
        else       gsrc = (const char*)vimg + pan + (w - 2) * 4096 + lane * 16;
    }

    #define STAGE(slot)                                                                   \
        {                                                                                 \
            _Pragma("unroll")                                                             \
            for (int j = 0; j < 4; ++j) {                                                 \
                __builtin_amdgcn_global_load_lds(                                         \
                    (const __attribute__((address_space(1))) unsigned*)(gsrc + j * 1024), \
                    (__attribute__((address_space(3))) unsigned*)&KV[slot][w * 2048 + j * 512], \
                    16, 0, 0);                                                            \
            }                                                                             \
            gsrc += 8192;                                                                 \
        }

    v16f oacc[2];
    #pragma unroll
    for (int mb = 0; mb < 2; ++mb)
        #pragma unroll
        for (int r = 0; r < 16; ++r) oacc[mb][r] = 0.0f;
    float rsum = 0.0f;

    // per-lane fragment offset (shorts): chunk u = (2ks+hi)*64 + mb*32 + l31
    //   -> offset = ks*1024 + mb*256 + rb,  rb = hi*512 + l31*8
    const int rb = hi * 512 + l31 * 8;

    // Drain Q loads so loop vmcnt counts see ONLY staging loads, then fill pipe 3 deep.
    asm volatile("s_waitcnt vmcnt(0)" ::: "memory");
    __builtin_amdgcn_sched_barrier(0);
    STAGE(0);
    STAGE(1);
    STAGE(2);

    #pragma unroll 4
    for (int it = 0; it < 32; ++it) {
        const int p = it & 3;

        // Outstanding before wait: tiles it, it+1, it+2 = 12 loads -> vmcnt(8)
        // retires tile it.  Tail: it=30 -> 8 outstanding -> vmcnt(4); it=31 -> 0.
        __builtin_amdgcn_sched_barrier(0);
        if (it <= 29)      asm volatile("s_waitcnt vmcnt(8)" ::: "memory");
        else if (it == 30) asm volatile("s_waitcnt vmcnt(4)" ::: "memory");
        else               asm volatile("s_waitcnt vmcnt(0)" ::: "memory");
        __builtin_amdgcn_s_barrier();
        __builtin_amdgcn_sched_barrier(0);

        // prefetch tile it+3 into slot (it+3)&3 = (it-1)&3 (its readers finished
        // during iter it-1; all waves passed the barrier above since)
        if (it <= 28) STAGE((it + 3) & 3);

        const short* Kp = &KV[p][0];
        const short* Vp = &KV[p][4096];

        // ---- S^T = K Q^T : 2 s-row-blocks x 4 k-steps ----
        v16f st[2];
        #pragma unroll
        for (int mb = 0; mb < 2; ++mb) {
            v16f z;
            #pragma unroll
            for (int r = 0; r < 16; ++r) z[r] = 0.0f;
            #pragma unroll
            for (int ks = 0; ks < 4; ++ks) {
                s8v kf = *(const s8v*)&Kp[ks * 1024 + mb * 256 + rb];
                z = __builtin_amdgcn_mfma_f32_32x32x16_bf16(kf, qf[ks], z, 0, 0, 0);
            }
            st[mb] = z;
        }

        // ---- exp2 numerator (tau pre-folded, no max-tracking), row sum, pack P frags ----
        #pragma unroll
        for (int mb = 0; mb < 2; ++mb)
            #pragma unroll
            for (int r = 0; r < 16; ++r)
                st[mb][r] = __builtin_amdgcn_exp2f(st[mb][r]);
        float s0 = 0.f, s1 = 0.f;
        #pragma unroll
        for (int r = 0; r < 16; ++r) { s0 += st[0][r]; s1 += st[1][r]; }
        rsum += s0 + s1;

        s8v pf[4];    // B-operand for PV, straight from C-layout registers
        #pragma unroll
        for (int tt = 0; tt < 4; ++tt) {
            int o = 8 * (tt & 1);
            const v16f& sv = st[tt >> 1];
            s4v lo = pack4bf(sv[o + 0], sv[o + 1], sv[o + 2], sv[o + 3]);
            s4v hs = pack4bf(sv[o + 4], sv[o + 5], sv[o + 6], sv[o + 7]);
            s8v f;
            #pragma unroll
            for (int j = 0; j < 4; ++j) { f[j] = lo[j]; f[4 + j] = hs[j]; }
            pf[tt] = f;
        }

        // ---- O^T += V^T P^T : 2 e-row-blocks x 4 k-steps ----
        #pragma unroll
        for (int mb = 0; mb < 2; ++mb) {
            v16f acc = oacc[mb];
            #pragma unroll
            for (int ks = 0; ks < 4; ++ks) {
                s8v vf = *(const s8v*)&Vp[ks * 1024 + mb * 256 + rb];
                acc = __builtin_amdgcn_mfma_f32_32x32x16_bf16(vf, pf[ks], acc, 0, 0, 0);
            }
            oacc[mb] = acc;
        }
    }

    // ---- denominator (single cross-half reduce) and store O^T -> O ----
    rsum += __shfl_xor(rsum, 32);
    const float inv = 1.0f / rsum;
    float* ob = out + ((size_t)b * LL + (size_t)mt * 128 + w * 32 + l31) * RSG + h * EE;
    #pragma unroll
    for (int mb = 0; mb < 2; ++mb)
        #pragma unroll
        for (int rq = 0; rq < 4; ++rq) {
            int e0 = 32 * mb + 8 * rq + 4 * hi;     // C-layout row = (reg&3)+8*(reg>>2)+4*hi
            v4f o4 = { oacc[mb][4 * rq + 0] * inv, oacc[mb][4 * rq + 1] * inv,
                       oacc[mb][4 * rq + 2] * inv, oacc[mb][4 * rq + 3] * inv };
            *(v4f*)(ob + e0) = o4;
        }
}

extern "C" void kernel_launch(void* const* d_in, const int* in_sizes, int n_in,
                              void* d_out, int out_size, void* d_ws, size_t ws_size,
                              hipStream_t stream) {
    const float* q     = (const float*)d_in[0];
    const float* k     = (const float*)d_in[1];
    const float* v     = (const float*)d_in[2];
    // d_in[3] = attn_mask (unused); d_in[5] = delta (drops out of softmax exactly)
    const float* tau   = (const float*)d_in[4];
    float* out = (float*)d_out;

    short* kimg = (short*)d_ws;                   // 4*2048*512 bf16 = 8.39 MB
    short* vimg = kimg + (size_t)4 * SS * RSG;    // 8.39 MB

    dsattn_prep<<<dim3(2048), dim3(256), 0, stream>>>(k, v, kimg, vimg);
    dsattn_main<<<dim3(512), dim3(256), 0, stream>>>(q, kimg, vimg, tau, out);
}

// Round 6
// 134.212 us; speedup vs baseline: 4.0671x; 1.0148x over previous
//
#include <hip/hip_runtime.h>
#include <hip/hip_bf16.h>
#include <stdint.h>

#define LL 2048
#define SS 2048
#define HH 8
#define EE 64
#define RSG 512   // global row stride in elements (H*E)

typedef float v4f  __attribute__((ext_vector_type(4)));
typedef float v16f __attribute__((ext_vector_type(16)));
typedef short s4v  __attribute__((ext_vector_type(4)));
typedef short s8v  __attribute__((ext_vector_type(8)));

// fp32 -> bf16 bits, round-to-nearest-even
__device__ __forceinline__ short f2bf(float f) {
    unsigned u = __float_as_uint(f);
    u = (u + 0x7fffu + ((u >> 16) & 1u)) >> 16;
    return (short)u;
}

__device__ __forceinline__ s4v pack4bf(float a, float b, float c, float d) {
    float2 ab = make_float2(a, b), cd = make_float2(c, d);
    __hip_bfloat162 r0 = __float22bfloat162_rn(ab);
    __hip_bfloat162 r1 = __float22bfloat162_rn(cd);
    s4v r;
    __builtin_memcpy(&r, &r0, 4);
    __builtin_memcpy(((char*)&r) + 4, &r1, 4);
    return r;
}

// ---------------- prepass ----------------
// Both K and V become per-(b,h,64-row-tile) IMAGES in k-chunk-major order so
// that every main-loop ds_read_b128 and every global_load_lds is fully linear
// (zero bank conflicts, zero XOR address math).
//
// K image: chunk u = echunk*64 + srow  holds K[srow][8*echunk .. +8) as bf16.
// V image: chunk u = c*64 + e          holds V[perm(c,j)][e], j=0..7, with
//   perm(c,j) = 16*(c>>1) + 4*(c&1) + 8*(j>>2) + (j&3)   (the PV k-permutation)
__global__ __launch_bounds__(256)
void dsattn_prep(const float* __restrict__ kk, const float* __restrict__ vv,
                 short* __restrict__ kimg, short* __restrict__ vimg)
{
    __shared__ float T[64][68];
    const int t = threadIdx.x;
    const int blk = blockIdx.x;
    if (blk < 1024) {
        const int vb = blk;                  // (b*8 + h)*32 + ts
        const int b = vb >> 8, h = (vb >> 5) & 7, ts = vb & 31;
        const float* kp = kk + ((size_t)b * SS + ts * 64) * RSG + h * EE;
        #pragma unroll
        for (int c = 0; c < 4; ++c) {
            int idx = c * 256 + t, s = idx >> 4, e0 = (idx & 15) << 2;
            *(v4f*)&T[s][e0] = *(const v4f*)(kp + (size_t)s * RSG + e0);
        }
        __syncthreads();
        short* dst = kimg + (size_t)vb * 4096;
        #pragma unroll
        for (int half = 0; half < 2; ++half) {
            int ci = half * 256 + t;         // chunk u = echunk*64 + srow
            int echunk = ci >> 6, srow = ci & 63;
            s8v ov;
            #pragma unroll
            for (int j = 0; j < 8; ++j) ov[j] = f2bf(T[srow][echunk * 8 + j]);
            *(s8v*)(dst + ci * 8) = ov;
        }
    } else {
        const int vb = blk - 1024;           // (b*8 + h)*32 + ts
        const int b = vb >> 8, h = (vb >> 5) & 7, ts = vb & 31;
        const float* vp = vv + ((size_t)b * SS + ts * 64) * RSG + h * EE;
        #pragma unroll
        for (int c = 0; c < 4; ++c) {
            int idx = c * 256 + t, s = idx >> 4, e0 = (idx & 15) << 2;
            *(v4f*)&T[s][e0] = *(const v4f*)(vp + (size_t)s * RSG + e0);
        }
        __syncthreads();
        short* dst = vimg + (size_t)vb * 4096;
        #pragma unroll
        for (int half = 0; half < 2; ++half) {
            int ci = half * 256 + t;         // chunk u = c*64 + e
            int c = ci >> 6, e = ci & 63;
            int sbase = 16 * (c >> 1) + 4 * (c & 1);
            s8v ov;
            #pragma unroll
            for (int j = 0; j < 8; ++j) {
                int s = sbase + 8 * (j >> 2) + (j & 3);
                ov[j] = f2bf(T[s][e]);
            }
            *(s8v*)(dst + ci * 8) = ov;
        }
    }
}

// ---------------- main: 128 Q rows/block, 4 waves x 32 rows, all-32x32x16 MFMA
// 2-tile SUPER-WINDOWS: each barrier window computes two S-tiles from one
// 32KB super-slot.  Within the fence-free window body, tile1's QK MFMA chain
// overlaps tile0's exp2/pack (trans/VALU) and PV — within-window ILP with NO
// loop-carried registers (the r3/r4 spill/serialization traps).
// 2 super-slots (64KB), counted vmcnt(8) waits (never 0 until the tail).
// XCD-bijective 1-D grid: each XCD owns 4 contiguous (b,h) panels.
__global__ __launch_bounds__(256, 2)
void dsattn_main(const float* __restrict__ q, const short* __restrict__ kimg,
                 const short* __restrict__ vimg, const float* __restrict__ tau,
                 float* __restrict__ out)
{
    // super-slot layout (shorts): [0..4095] K(t0), [4096..8191] V(t0),
    //                             [8192..12287] K(t1), [12288..16383] V(t1)
    __shared__ short KV[2][16384];

    const int t    = threadIdx.x;
    const int lane = t & 63;
    const int w    = t >> 6;
    const int l31  = lane & 31;
    const int hi   = lane >> 5;

    // XCD-aware decode: 512 blocks, 8 XCDs, 64 consecutive work-units per XCD.
    const int hw = blockIdx.x;
    const int wu = (hw & 7) * 64 + (hw >> 3);
    const int mt = wu & 15;
    const int h  = (wu >> 4) & 7;
    const int b  = wu >> 7;

    const float scf = 0.125f * 1.44269504088896f * tau[b];  // tau*scale*log2e folded into Q

    // ---- Q B-frags: lane holds Q[w*32+l31][e = 16ks + 8hi + j], pre-scaled ----
    s8v qf[4];
    {
        const float* qb = q + ((size_t)b * LL + (size_t)mt * 128 + w * 32 + l31) * RSG
                            + h * EE + 8 * hi;
        #pragma unroll
        for (int ks = 0; ks < 4; ++ks) {
            v4f a0 = *(const v4f*)(qb + 16 * ks);
            v4f a1 = *(const v4f*)(qb + 16 * ks + 4);
            s4v p0 = pack4bf(a0[0] * scf, a0[1] * scf, a0[2] * scf, a0[3] * scf);
            s4v p1 = pack4bf(a1[0] * scf, a1[1] * scf, a1[2] * scf, a1[3] * scf);
            s8v f;
            #pragma unroll
            for (int j = 0; j < 4; ++j) { f[j] = p0[j]; f[4 + j] = p1[j]; }
            qf[ks] = f;
        }
    }

    // ---- staging source: fully linear (K image: waves 0,1; V image: waves 2,3) ----
    const char* gsrc;
    {
        const size_t pan = (size_t)((b * 8 + h) * 32) * 8192;   // 32 tiles x 8KB
        if (w < 2) gsrc = (const char*)kimg + pan + w * 4096 + lane * 16;
        else       gsrc = (const char*)vimg + pan + (w - 2) * 4096 + lane * 16;
    }

    // one SUPERSTAGE = 8 loads/wave = two consecutive 8KB tiles
    #define SUPERSTAGE(slot)                                                              \
        {                                                                                 \
            _Pragma("unroll")                                                             \
            for (int j = 0; j < 4; ++j) {                                                 \
                __builtin_amdgcn_global_load_lds(                                         \
                    (const __attribute__((address_space(1))) unsigned*)(gsrc + j * 1024), \
                    (__attribute__((address_space(3))) unsigned*)&KV[slot][w * 2048 + j * 512], \
                    16, 0, 0);                                                            \
            }                                                                             \
            _Pragma("unroll")                                                             \
            for (int j = 0; j < 4; ++j) {                                                 \
                __builtin_amdgcn_global_load_lds(                                         \
                    (const __attribute__((address_space(1))) unsigned*)(gsrc + 8192 + j * 1024), \
                    (__attribute__((address_space(3))) unsigned*)&KV[slot][8192 + w * 2048 + j * 512], \
                    16, 0, 0);                                                            \
            }                                                                             \
            gsrc += 16384;                                                                \
        }

    v16f oacc[2];
    #pragma unroll
    for (int mb = 0; mb < 2; ++mb)
        #pragma unroll
        for (int r = 0; r < 16; ++r) oacc[mb][r] = 0.0f;
    float rsum = 0.0f;

    // per-lane fragment offset (shorts): chunk u = (2ks+hi)*64 + mb*32 + l31
    //   -> offset = ks*1024 + mb*256 + rb,  rb = hi*512 + l31*8
    const int rb = hi * 512 + l31 * 8;

    // Drain Q loads so loop vmcnt counts see ONLY staging loads; fill both slots.
    asm volatile("s_waitcnt vmcnt(0)" ::: "memory");
    __builtin_amdgcn_sched_barrier(0);
    SUPERSTAGE(0);
    SUPERSTAGE(1);

    #pragma unroll 1
    for (int sw = 0; sw < 16; ++sw) {
        const int p = sw & 1;

        // Outstanding: supers sw, sw+1 = 16 loads -> vmcnt(8) retires super sw.
        // Tail sw=15: only 8 outstanding -> vmcnt(0).
        __builtin_amdgcn_sched_barrier(0);
        if (sw <= 14) asm volatile("s_waitcnt vmcnt(8)" ::: "memory");
        else          asm volatile("s_waitcnt vmcnt(0)" ::: "memory");
        __builtin_amdgcn_s_barrier();          // everyone's super-sw portions landed
        __builtin_amdgcn_sched_barrier(0);

        // ---- window body (fence-free): QK(t0), QK(t1), exp/pack/PV per tile ----
        v16f st[2][2];                         // [tile][mb]
        #pragma unroll
        for (int tl = 0; tl < 2; ++tl) {
            const short* Kp = &KV[p][tl * 8192];
            #pragma unroll
            for (int mb = 0; mb < 2; ++mb) {
                v16f z;
                #pragma unroll
                for (int r = 0; r < 16; ++r) z[r] = 0.0f;
                #pragma unroll
                for (int ks = 0; ks < 4; ++ks) {
                    s8v kf = *(const s8v*)&Kp[ks * 1024 + mb * 256 + rb];
                    z = __builtin_amdgcn_mfma_f32_32x32x16_bf16(kf, qf[ks], z, 0, 0, 0);
                }
                st[tl][mb] = z;
            }
        }

        #pragma unroll
        for (int tl = 0; tl < 2; ++tl) {
            // exp2 numerator (tau pre-folded), row sum
            #pragma unroll
            for (int mb = 0; mb < 2; ++mb)
                #pragma unroll
                for (int r = 0; r < 16; ++r)
                    st[tl][mb][r] = __builtin_amdgcn_exp2f(st[tl][mb][r]);
            float s0 = 0.f, s1 = 0.f;
            #pragma unroll
            for (int r = 0; r < 16; ++r) { s0 += st[tl][0][r]; s1 += st[tl][1][r]; }
            rsum += s0 + s1;

            // pack P frags (B-operand for PV, straight from C-layout registers)
            s8v pf[4];
            #pragma unroll
            for (int tt = 0; tt < 4; ++tt) {
                int o = 8 * (tt & 1);
                const v16f& sv = st[tl][tt >> 1];
                s4v lo = pack4bf(sv[o + 0], sv[o + 1], sv[o + 2], sv[o + 3]);
                s4v hs = pack4bf(sv[o + 4], sv[o + 5], sv[o + 6], sv[o + 7]);
                s8v f;
                #pragma unroll
                for (int j = 0; j < 4; ++j) { f[j] = lo[j]; f[4 + j] = hs[j]; }
                pf[tt] = f;
            }

            // O^T += V^T P^T
            const short* Vp = &KV[p][tl * 8192 + 4096];
            #pragma unroll
            for (int mb = 0; mb < 2; ++mb) {
                v16f acc = oacc[mb];
                #pragma unroll
                for (int ks = 0; ks < 4; ++ks) {
                    s8v vf = *(const s8v*)&Vp[ks * 1024 + mb * 256 + rb];
                    acc = __builtin_amdgcn_mfma_f32_32x32x16_bf16(vf, pf[ks], acc, 0, 0, 0);
                }
                oacc[mb] = acc;
            }
        }

        // re-stage the just-computed slot with super sw+2 (all waves must be done
        // reading slot p first -> barrier), loads fly under window sw+1's compute
        if (sw <= 13) {
            __builtin_amdgcn_sched_barrier(0);
            __builtin_amdgcn_s_barrier();
            __builtin_amdgcn_sched_barrier(0);
            SUPERSTAGE(p);
        }
    }

    // ---- denominator (single cross-half reduce) and store O^T -> O ----
    rsum += __shfl_xor(rsum, 32);
    const float inv = 1.0f / rsum;
    float* ob = out + ((size_t)b * LL + (size_t)mt * 128 + w * 32 + l31) * RSG + h * EE;
    #pragma unroll
    for (int mb = 0; mb < 2; ++mb)
        #pragma unroll
        for (int rq = 0; rq < 4; ++rq) {
            int e0 = 32 * mb + 8 * rq + 4 * hi;     // C-layout row = (reg&3)+8*(reg>>2)+4*hi
            v4f o4 = { oacc[mb][4 * rq + 0] * inv, oacc[mb][4 * rq + 1] * inv,
                       oacc[mb][4 * rq + 2] * inv, oacc[mb][4 * rq + 3] * inv };
            *(v4f*)(ob + e0) = o4;
        }
}

extern "C" void kernel_launch(void* const* d_in, const int* in_sizes, int n_in,
                              void* d_out, int out_size, void* d_ws, size_t ws_size,
                              hipStream_t stream) {
    const float* q     = (const float*)d_in[0];
    const float* k     = (const float*)d_in[1];
    const float* v     = (const float*)d_in[2];
    // d_in[3] = attn_mask (unused); d_in[5] = delta (drops out of softmax exactly)
    const float* tau   = (const float*)d_in[4];
    float* out = (float*)d_out;

    short* kimg = (short*)d_ws;                   // 4*2048*512 bf16 = 8.39 MB
    short* vimg = kimg + (size_t)4 * SS * RSG;    // 8.39 MB

    dsattn_prep<<<dim3(2048), dim3(256), 0, stream>>>(k, v, kimg, vimg);
    dsattn_main<<<dim3(512), dim3(256), 0, stream>>>(q, kimg, vimg, tau, out);
}